// Round 1
// baseline (8898.390 us; speedup 1.0000x reference)
//
#include <hip/hip_runtime.h>
#include <math.h>

// Sizes (fixed by the problem, but derived from in_sizes where cheap)
#define D_IN 100
#define H    100
#define SEQL 30

// ---------------------------------------------------------------------------
// Kernel 0: Wemb[v, g] = dot(emb[v,:], W_ih[g,:]) + b_ih[g]   (v<V, g<300)
// ---------------------------------------------------------------------------
__global__ void k_wemb(const float* __restrict__ emb, const float* __restrict__ W_ih,
                       const float* __restrict__ b_ih, float* __restrict__ Wemb, int total) {
    int t = blockIdx.x * blockDim.x + threadIdx.x;
    if (t >= total) return;
    int v = t / 300, g = t % 300;
    const float* e = emb + (long)v * D_IN;
    const float* w = W_ih + (long)g * D_IN;
    float acc = 0.f;
#pragma unroll 4
    for (int d = 0; d < D_IN; ++d) acc += e[d] * w[d];
    Wemb[t] = acc + b_ih[g];
}

// ---------------------------------------------------------------------------
// GRU: one thread per node, h[100] register-resident across all 30 steps.
// hnew goes to LDS (dynamic index by rolled j), stride 101 to avoid conflicts.
// W_hh / b_hh indices are wave-uniform -> scalar loads.
// ---------------------------------------------------------------------------
__global__ __launch_bounds__(128) void k_gru(const int* __restrict__ tok,
                                             const float* __restrict__ h0,
                                             const float* __restrict__ Wemb,
                                             const float* __restrict__ W_hh,
                                             const float* __restrict__ b_hh,
                                             float* __restrict__ hout, int n_nodes) {
    __shared__ float lds[128 * 101];
    int n = blockIdx.x * blockDim.x + threadIdx.x;
    if (n >= n_nodes) return;

    float h[H];
#pragma unroll
    for (int d = 0; d < H; ++d) h[d] = h0[(long)n * H + d];

    float* my = lds + threadIdx.x * 101;

#pragma unroll 1
    for (int l = 0; l < SEQL; ++l) {
        int t = tok[(long)n * SEQL + l];
        const float* wx = Wemb + (long)t * 300;
#pragma unroll 1
        for (int j = 0; j < H; ++j) {
            const float* wr = W_hh + j * H;        // uniform address -> s_load
            const float* wz = wr + 100 * H;
            const float* wn = wz + 100 * H;
            float ar = 0.f, az = 0.f, an = 0.f;
#pragma unroll
            for (int d = 0; d < H; ++d) {
                ar += wr[d] * h[d];
                az += wz[d] * h[d];
                an += wn[d] * h[d];
            }
            float r  = 1.f / (1.f + expf(-(wx[j]         + ar + b_hh[j])));
            float z  = 1.f / (1.f + expf(-(wx[100 + j]   + az + b_hh[100 + j])));
            float nn = tanhf(wx[200 + j] + r * (an + b_hh[200 + j]));
            my[j] = (1.f - z) * nn + z * h[j];
        }
#pragma unroll
        for (int d = 0; d < H; ++d) h[d] = my[d];
    }
#pragma unroll
    for (int d = 0; d < H; ++d) hout[(long)n * H + d] = h[d];
}

// ---------------------------------------------------------------------------
// Degree (in-edges by dst), then dinv = rsqrt(deg + 1) in-place
// ---------------------------------------------------------------------------
__global__ void k_deg(const int* __restrict__ dst, float* __restrict__ deg, int E) {
    int e = blockIdx.x * blockDim.x + threadIdx.x;
    if (e < E) atomicAdd(&deg[dst[e]], 1.0f);
}

__global__ void k_dinv(float* __restrict__ deg, int N) {
    int n = blockIdx.x * blockDim.x + threadIdx.x;
    if (n < N) deg[n] = rsqrtf(deg[n] + 1.0f);
}

// ---------------------------------------------------------------------------
// xw[n, j] = sum_d x[n, d] * W[d, j]   (j < 100; K = inner dim)
// ---------------------------------------------------------------------------
template <int K>
__global__ void k_mm(const float* __restrict__ x, const float* __restrict__ W,
                     float* __restrict__ out, int total) {
    int t = blockIdx.x * blockDim.x + threadIdx.x;
    if (t >= total) return;
    int n = t / 100, j = t % 100;
    const float* xr = x + (long)n * K;
    float acc = 0.f;
#pragma unroll 4
    for (int d = 0; d < K; ++d) acc += xr[d] * W[d * 100 + j];
    out[t] = acc;
}

// ---------------------------------------------------------------------------
// Edge aggregation: agg[dst, j] += xw[src, j] * dinv[src] * dinv[dst]
// ---------------------------------------------------------------------------
__global__ void k_agg(const int* __restrict__ src, const int* __restrict__ dst,
                      const float* __restrict__ xw, const float* __restrict__ dinv,
                      float* __restrict__ agg, int total /* E*100 */) {
    int t = blockIdx.x * blockDim.x + threadIdx.x;
    if (t >= total) return;
    int e = t / 100, j = t % 100;
    int s = src[e], d0 = dst[e];
    float c = dinv[s] * dinv[d0];
    atomicAdd(&agg[(long)d0 * 100 + j], xw[(long)s * 100 + j] * c);
}

// ---------------------------------------------------------------------------
// Combine 1: xc1 = agg + xw*dinv^2 + b1 ; xbig = relu([xc1, hn[idx]])
// ---------------------------------------------------------------------------
__global__ void k_comb1(const float* __restrict__ agg, const float* __restrict__ xw,
                        const float* __restrict__ dinv, const float* __restrict__ b1,
                        const float* __restrict__ hn, const int* __restrict__ idx,
                        float* __restrict__ xc1, float* __restrict__ xbig, int total /* N*100 */) {
    int t = blockIdx.x * blockDim.x + threadIdx.x;
    if (t >= total) return;
    int n = t / 100, j = t % 100;
    float di = dinv[n];
    float v = agg[t] + xw[t] * di * di + b1[j];
    xc1[t] = v;
    xbig[(long)n * 200 + j] = fmaxf(v, 0.f);
    float rv = hn[(long)idx[n] * 100 + j];
    xbig[(long)n * 200 + 100 + j] = fmaxf(rv, 0.f);
}

// ---------------------------------------------------------------------------
// Output: out = [relu(agg2 + xw2*dinv^2 + b2), xc1[idx]]
// ---------------------------------------------------------------------------
__global__ void k_out(const float* __restrict__ agg, const float* __restrict__ xw,
                      const float* __restrict__ dinv, const float* __restrict__ b2,
                      const float* __restrict__ xc1, const int* __restrict__ idx,
                      float* __restrict__ out, int total /* N*100 */) {
    int t = blockIdx.x * blockDim.x + threadIdx.x;
    if (t >= total) return;
    int n = t / 100, j = t % 100;
    float di = dinv[n];
    float v = agg[t] + xw[t] * di * di + b2[j];
    out[(long)n * 200 + j] = fmaxf(v, 0.f);
    out[(long)n * 200 + 100 + j] = xc1[(long)idx[n] * 100 + j];
}

// ---------------------------------------------------------------------------
extern "C" void kernel_launch(void* const* d_in, const int* in_sizes, int n_in,
                              void* d_out, int out_size, void* d_ws, size_t ws_size,
                              hipStream_t stream) {
    const int*   feat    = (const int*)d_in[0];    // [N, 30]
    const int*   edges   = (const int*)d_in[1];    // [2, E]
    const int*   indices = (const int*)d_in[2];    // [N]
    const float* h0      = (const float*)d_in[3];  // [1, N, 100]
    const float* emb     = (const float*)d_in[4];  // [V, 100]
    const float* W_ih    = (const float*)d_in[5];  // [300, 100]
    const float* W_hh    = (const float*)d_in[6];  // [300, 100]
    const float* b_ih    = (const float*)d_in[7];  // [300]
    const float* b_hh    = (const float*)d_in[8];  // [300]
    const float* W1      = (const float*)d_in[9];  // [100, 100]
    const float* b1      = (const float*)d_in[10]; // [100]
    const float* W2      = (const float*)d_in[11]; // [200, 100]
    const float* b2      = (const float*)d_in[12]; // [100]
    float* out = (float*)d_out;

    const int N = in_sizes[2];
    const int E = in_sizes[1] / 2;
    const int V = in_sizes[4] / D_IN;
    const int* src = edges;
    const int* dst = edges + E;

    // Workspace layout (floats). Wemb region (15M) is reused for the GCN
    // xw/agg buffers after the GRU finishes (they are <= 12M floats total).
    float* ws   = (float*)d_ws;
    float* hbuf = ws;                         // N*100       = 6.0M
    float* Wemb = hbuf + (long)N * H;         // V*300       = 15.0M
    float* xwA  = Wemb;                       // reuse: N*100
    float* aggA = Wemb + (long)N * 100;       // reuse: N*100
    float* xc1  = Wemb + (long)V * 300;       // N*100       = 6.0M
    float* xbig = xc1 + (long)N * 100;        // N*200       = 12.0M
    float* dinv = xbig + (long)N * 200;       // N
    (void)ws_size; (void)n_in; (void)out_size;

    const int B = 256;

    // degree (dinv buffer doubles as deg accumulator)
    hipMemsetAsync(dinv, 0, (size_t)N * sizeof(float), stream);
    k_deg<<<(E + B - 1) / B, B, 0, stream>>>(dst, dinv, E);

    // Wemb = emb @ W_ih^T + b_ih
    {
        int total = V * 300;
        k_wemb<<<(total + B - 1) / B, B, 0, stream>>>(emb, W_ih, b_ih, Wemb, total);
    }

    // GRU (reads Wemb; writes hbuf)
    k_gru<<<(N + 127) / 128, 128, 0, stream>>>(feat, h0, Wemb, W_hh, b_hh, hbuf, N);

    k_dinv<<<(N + B - 1) / B, B, 0, stream>>>(dinv, N);

    // GCN conv 1: xwA = hn @ W1 ; aggA = scatter ; xc1/xbig combine
    {
        int total = N * 100;
        k_mm<100><<<(total + B - 1) / B, B, 0, stream>>>(hbuf, W1, xwA, total);
        hipMemsetAsync(aggA, 0, (size_t)total * sizeof(float), stream);
        int etot = E * 100;
        k_agg<<<(etot + B - 1) / B, B, 0, stream>>>(src, dst, xwA, dinv, aggA, etot);
        k_comb1<<<(total + B - 1) / B, B, 0, stream>>>(aggA, xwA, dinv, b1, hbuf, indices,
                                                      xc1, xbig, total);
    }

    // GCN conv 2: xwA = xbig @ W2 ; aggA = scatter ; final output
    {
        int total = N * 100;
        k_mm<200><<<(total + B - 1) / B, B, 0, stream>>>(xbig, W2, xwA, total);
        hipMemsetAsync(aggA, 0, (size_t)total * sizeof(float), stream);
        int etot = E * 100;
        k_agg<<<(etot + B - 1) / B, B, 0, stream>>>(src, dst, xwA, dinv, aggA, etot);
        k_out<<<(total + B - 1) / B, B, 0, stream>>>(aggA, xwA, dinv, b2, xc1, indices,
                                                    out, total);
    }
}